// Round 1
// baseline (702.741 us; speedup 1.0000x reference)
//
#include <hip/hip_runtime.h>

// Shapes (fixed by the reference): B=4, S=2048 -> M=8192; D_IN=K=4096; D_OUT=N=4096; R=16
constexpr int M = 8192;
constexpr int N = 4096;
constexpr int K = 4096;
constexpr float SCALING = 2.0f; // 32/16

typedef __bf16 bf16x8 __attribute__((ext_vector_type(8)));
typedef __bf16 bf16x4 __attribute__((ext_vector_type(4)));
typedef float  f32x4  __attribute__((ext_vector_type(4)));

// ---------------------------------------------------------------------------
// Kernel 1: cast x (fp32) -> bf16, 8 elements / thread
// ---------------------------------------------------------------------------
__global__ __launch_bounds__(256) void qlora_cast_x(const float* __restrict__ x,
                                                    __bf16* __restrict__ xb) {
    const size_t i = ((size_t)blockIdx.x * 256 + threadIdx.x) * 8;
    const float4 v0 = *(const float4*)(x + i);
    const float4 v1 = *(const float4*)(x + i + 4);
    bf16x8 o;
    o[0] = (__bf16)v0.x; o[1] = (__bf16)v0.y; o[2] = (__bf16)v0.z; o[3] = (__bf16)v0.w;
    o[4] = (__bf16)v1.x; o[5] = (__bf16)v1.y; o[6] = (__bf16)v1.z; o[7] = (__bf16)v1.w;
    *(bf16x8*)(xb + i) = o;
}

// ---------------------------------------------------------------------------
// Kernel 2: W_eff[o,i] = w_int[o,i]*scale + 2 * sum_r loraB[o,r]*loraA[r,i]  (bf16)
// One block per output row o; 256 threads x 4 iters x 4 elements.
// ---------------------------------------------------------------------------
__global__ __launch_bounds__(256) void qlora_prep_w(const int* __restrict__ wi,
                                                    const float* __restrict__ wscale,
                                                    const float* __restrict__ lA,
                                                    const float* __restrict__ lB,
                                                    __bf16* __restrict__ W) {
    const int o = blockIdx.x;
    const float s = wscale[0];
    float b[16];
#pragma unroll
    for (int r = 0; r < 16; ++r) b[r] = lB[o * 16 + r];

#pragma unroll
    for (int it = 0; it < 4; ++it) {
        const int i0 = it * 1024 + threadIdx.x * 4;
        const int4 w4 = *(const int4*)(wi + (size_t)o * K + i0);
        float a0 = 0.f, a1 = 0.f, a2 = 0.f, a3 = 0.f;
#pragma unroll
        for (int r = 0; r < 16; ++r) {
            const float4 a4 = *(const float4*)(lA + r * K + i0);
            a0 += b[r] * a4.x; a1 += b[r] * a4.y;
            a2 += b[r] * a4.z; a3 += b[r] * a4.w;
        }
        bf16x4 v;
        v[0] = (__bf16)((float)w4.x * s + SCALING * a0);
        v[1] = (__bf16)((float)w4.y * s + SCALING * a1);
        v[2] = (__bf16)((float)w4.z * s + SCALING * a2);
        v[3] = (__bf16)((float)w4.w * s + SCALING * a3);
        *(bf16x4*)(W + (size_t)o * K + i0) = v;
    }
}

// ---------------------------------------------------------------------------
// Kernel 3: C[M,N] = Xbf[M,K] @ Wbf[N,K]^T   (m97-structure bf16 GEMM)
// 128x128 block tile, BK=32, 4 waves, 4x4 16x16x32 MFMA per wave,
// global_load_lds width=16 staging, 2-barrier K-loop.
// ---------------------------------------------------------------------------
__device__ __forceinline__ void async16(const __bf16* g, __bf16* l) {
    __builtin_amdgcn_global_load_lds(
        (const __attribute__((address_space(1))) unsigned int*)(unsigned long long)g,
        (__attribute__((address_space(3))) unsigned int*)(unsigned int)(unsigned long long)l,
        16, 0, 0);
}

__global__ __launch_bounds__(256) void qlora_gemm_bt(const __bf16* __restrict__ A,
                                                     const __bf16* __restrict__ B,
                                                     float* __restrict__ C) {
    __shared__ __align__(16) __bf16 As[128 * 32];
    __shared__ __align__(16) __bf16 Bs[128 * 32];

    const int tid  = threadIdx.x;
    const int w    = tid >> 6;      // wave 0..3
    const int lane = tid & 63;
    const int quad = lane >> 4;     // 0..3
    const int lb   = lane & 15;
    const int wm   = w >> 1;        // 0..1
    const int wn   = w & 1;         // 0..1

    // staging lane decomposition: 64 lanes cover 16 rows x 4 k-chunks of 8
    const int r16 = lane >> 2;           // 0..15
    const int kc  = (lane & 3) * 8;      // 0,8,16,24

    const size_t mBase = (size_t)blockIdx.y * 128;
    const size_t nBase = (size_t)blockIdx.x * 128;

    const int t0 = w * 2, t1 = w * 2 + 1;
    const __bf16* gA0 = A + (mBase + t0 * 16 + r16) * K + kc;
    const __bf16* gA1 = A + (mBase + t1 * 16 + r16) * K + kc;
    const __bf16* gB0 = B + (nBase + t0 * 16 + r16) * K + kc;
    const __bf16* gB1 = B + (nBase + t1 * 16 + r16) * K + kc;
    __bf16* lA0 = As + t0 * 512;
    __bf16* lA1 = As + t1 * 512;
    __bf16* lB0 = Bs + t0 * 512;
    __bf16* lB1 = Bs + t1 * 512;

    f32x4 acc[4][4] = {};

    for (int kt = 0; kt < K; kt += 32) {
        async16(gA0 + kt, lA0);
        async16(gA1 + kt, lA1);
        async16(gB0 + kt, lB0);
        async16(gB1 + kt, lB1);
        __syncthreads();   // vmcnt(0) drain + barrier: tiles visible

        bf16x8 af[4], bfr[4];
#pragma unroll
        for (int t = 0; t < 4; ++t) {
            af[t]  = *(const bf16x8*)(As + (wm * 64 + t * 16 + lb) * 32 + quad * 8);
            bfr[t] = *(const bf16x8*)(Bs + (wn * 64 + t * 16 + lb) * 32 + quad * 8);
        }
#pragma unroll
        for (int tm = 0; tm < 4; ++tm)
#pragma unroll
            for (int tn = 0; tn < 4; ++tn)
                acc[tm][tn] = __builtin_amdgcn_mfma_f32_16x16x32_bf16(
                    af[tm], bfr[tn], acc[tm][tn], 0, 0, 0);
        __syncthreads();   // all waves done reading before next overwrite
    }

    // Epilogue: D layout col = lane&15, row = quad*4 + reg
#pragma unroll
    for (int tm = 0; tm < 4; ++tm) {
        const size_t m0 = mBase + wm * 64 + tm * 16 + quad * 4;
#pragma unroll
        for (int tn = 0; tn < 4; ++tn) {
            const size_t n0 = nBase + wn * 64 + tn * 16 + lb;
            float* p = C + m0 * N + n0;
            p[0 * (size_t)N] = acc[tm][tn][0];
            p[1 * (size_t)N] = acc[tm][tn][1];
            p[2 * (size_t)N] = acc[tm][tn][2];
            p[3 * (size_t)N] = acc[tm][tn][3];
        }
    }
}

// ---------------------------------------------------------------------------
extern "C" void kernel_launch(void* const* d_in, const int* in_sizes, int n_in,
                              void* d_out, int out_size, void* d_ws, size_t ws_size,
                              hipStream_t stream) {
    const float* x      = (const float*)d_in[0];
    const int*   wint   = (const int*)d_in[1];
    const float* wscale = (const float*)d_in[2];
    const float* lA     = (const float*)d_in[3];
    const float* lB     = (const float*)d_in[4];
    float* out = (float*)d_out;

    __bf16* Xb = (__bf16*)d_ws;                                   // M*K*2 = 64 MiB
    __bf16* Wb = (__bf16*)((char*)d_ws + (size_t)M * K * 2);      // N*K*2 = 32 MiB

    // 33,554,432 x-elements / 8 per thread / 256 threads = 16384 blocks
    qlora_cast_x<<<16384, 256, 0, stream>>>(x, Xb);
    qlora_prep_w<<<4096, 256, 0, stream>>>(wint, wscale, lA, lB, Wb);
    qlora_gemm_bt<<<dim3(N / 128, M / 128), 256, 0, stream>>>(Xb, Wb, out);
}

// Round 2
// 687.532 us; speedup vs baseline: 1.0221x; 1.0221x over previous
//
#include <hip/hip_runtime.h>

// Shapes (fixed by the reference): B=4, S=2048 -> M=8192; D_IN=K=4096; D_OUT=N=4096; R=16
constexpr int M = 8192;
constexpr int N = 4096;
constexpr int K = 4096;
constexpr float SCALING = 2.0f; // 32/16

typedef __bf16 bf16x8 __attribute__((ext_vector_type(8)));
typedef __bf16 bf16x4 __attribute__((ext_vector_type(4)));
typedef float  f32x4  __attribute__((ext_vector_type(4)));

// ---------------------------------------------------------------------------
// Kernel 1: cast x (fp32) -> bf16, 8 elements / thread
// ---------------------------------------------------------------------------
__global__ __launch_bounds__(256) void qlora_cast_x(const float* __restrict__ x,
                                                    __bf16* __restrict__ xb) {
    const size_t i = ((size_t)blockIdx.x * 256 + threadIdx.x) * 8;
    const float4 v0 = *(const float4*)(x + i);
    const float4 v1 = *(const float4*)(x + i + 4);
    bf16x8 o;
    o[0] = (__bf16)v0.x; o[1] = (__bf16)v0.y; o[2] = (__bf16)v0.z; o[3] = (__bf16)v0.w;
    o[4] = (__bf16)v1.x; o[5] = (__bf16)v1.y; o[6] = (__bf16)v1.z; o[7] = (__bf16)v1.w;
    *(bf16x8*)(xb + i) = o;
}

// ---------------------------------------------------------------------------
// Kernel 2: W_eff[o,i] = w_int[o,i]*scale + 2 * sum_r loraB[o,r]*loraA[r,i]  (bf16)
// ---------------------------------------------------------------------------
__global__ __launch_bounds__(256) void qlora_prep_w(const int* __restrict__ wi,
                                                    const float* __restrict__ wscale,
                                                    const float* __restrict__ lA,
                                                    const float* __restrict__ lB,
                                                    __bf16* __restrict__ W) {
    const int o = blockIdx.x;
    const float s = wscale[0];
    float b[16];
#pragma unroll
    for (int r = 0; r < 16; ++r) b[r] = lB[o * 16 + r];

#pragma unroll
    for (int it = 0; it < 4; ++it) {
        const int i0 = it * 1024 + threadIdx.x * 4;
        const int4 w4 = *(const int4*)(wi + (size_t)o * K + i0);
        float a0 = 0.f, a1 = 0.f, a2 = 0.f, a3 = 0.f;
#pragma unroll
        for (int r = 0; r < 16; ++r) {
            const float4 a4 = *(const float4*)(lA + r * K + i0);
            a0 += b[r] * a4.x; a1 += b[r] * a4.y;
            a2 += b[r] * a4.z; a3 += b[r] * a4.w;
        }
        bf16x4 v;
        v[0] = (__bf16)((float)w4.x * s + SCALING * a0);
        v[1] = (__bf16)((float)w4.y * s + SCALING * a1);
        v[2] = (__bf16)((float)w4.z * s + SCALING * a2);
        v[3] = (__bf16)((float)w4.w * s + SCALING * a3);
        *(bf16x4*)(W + (size_t)o * K + i0) = v;
    }
}

// ---------------------------------------------------------------------------
// Kernel 3: C[M,N] = Xbf[M,K] @ Wbf[N,K]^T   (m97 structure + XOR bank swizzle)
//
// LDS layout: 16B chunk (row, q) of the 128x32 tile lives at slot
//   row*64B + (q ^ ((row>>1)&3))*16B
// global_load_lds forces slot = lane*16B from a wave-uniform base, so the
// swizzle is applied by permuting WHICH k-chunk each lane fetches.
// Read-side bank group = 16*(lb&1) + 4*(quad^((lb>>1)&3)) -> 8 groups x 2
// lanes = 2-way aliasing = free (m136).
// ---------------------------------------------------------------------------
__device__ __forceinline__ void async16(const __bf16* g, __bf16* l) {
    __builtin_amdgcn_global_load_lds(
        (const __attribute__((address_space(1))) unsigned int*)(unsigned long long)g,
        (__attribute__((address_space(3))) unsigned int*)(unsigned int)(unsigned long long)l,
        16, 0, 0);
}

__global__ __launch_bounds__(256) void qlora_gemm_bt(const __bf16* __restrict__ A,
                                                     const __bf16* __restrict__ B,
                                                     float* __restrict__ C) {
    __shared__ __align__(16) __bf16 As[128 * 32];
    __shared__ __align__(16) __bf16 Bs[128 * 32];

    const int tid  = threadIdx.x;
    const int w    = tid >> 6;      // wave 0..3
    const int lane = tid & 63;
    const int quad = lane >> 4;     // 0..3
    const int lb   = lane & 15;
    const int wm   = w >> 1;        // 0..1
    const int wn   = w & 1;         // 0..1

    // staging lane decomposition: lane l -> row r16 = l>>2, LDS slot l&3.
    // Swizzle: slot s holds global k-chunk q = s ^ ((r16>>1)&3).
    const int r16   = lane >> 2;                              // 0..15
    const int kc_sw = (((lane & 3) ^ ((r16 >> 1) & 3)) * 8);  // swizzled k offset (elems)

    const size_t mBase = (size_t)blockIdx.y * 128;
    const size_t nBase = (size_t)blockIdx.x * 128;

    const int t0 = w * 2, t1 = w * 2 + 1;
    const __bf16* gA0 = A + (mBase + t0 * 16 + r16) * K + kc_sw;
    const __bf16* gA1 = A + (mBase + t1 * 16 + r16) * K + kc_sw;
    const __bf16* gB0 = B + (nBase + t0 * 16 + r16) * K + kc_sw;
    const __bf16* gB1 = B + (nBase + t1 * 16 + r16) * K + kc_sw;
    __bf16* lA0 = As + t0 * 512;
    __bf16* lA1 = As + t1 * 512;
    __bf16* lB0 = Bs + t0 * 512;
    __bf16* lB1 = Bs + t1 * 512;

    // fragment read: row = wm*64 + t*16 + lb, want chunk q=quad ->
    // stored at slot quad ^ ((row>>1)&3) = quad ^ ((lb>>1)&3)
    const int rdoff = ((quad ^ ((lb >> 1) & 3)) * 8);

    f32x4 acc[4][4] = {};

    for (int kt = 0; kt < K; kt += 32) {
        async16(gA0 + kt, lA0);
        async16(gA1 + kt, lA1);
        async16(gB0 + kt, lB0);
        async16(gB1 + kt, lB1);
        __syncthreads();   // vmcnt(0) drain + barrier: tiles visible

        bf16x8 af[4], bfr[4];
#pragma unroll
        for (int t = 0; t < 4; ++t) {
            af[t]  = *(const bf16x8*)(As + (wm * 64 + t * 16 + lb) * 32 + rdoff);
            bfr[t] = *(const bf16x8*)(Bs + (wn * 64 + t * 16 + lb) * 32 + rdoff);
        }
#pragma unroll
        for (int tm = 0; tm < 4; ++tm)
#pragma unroll
            for (int tn = 0; tn < 4; ++tn)
                acc[tm][tn] = __builtin_amdgcn_mfma_f32_16x16x32_bf16(
                    af[tm], bfr[tn], acc[tm][tn], 0, 0, 0);
        __syncthreads();   // all waves done reading before next overwrite
    }

    // Epilogue: D layout col = lane&15, row = quad*4 + reg
#pragma unroll
    for (int tm = 0; tm < 4; ++tm) {
        const size_t m0 = mBase + wm * 64 + tm * 16 + quad * 4;
#pragma unroll
        for (int tn = 0; tn < 4; ++tn) {
            const size_t n0 = nBase + wn * 64 + tn * 16 + lb;
            float* p = C + m0 * N + n0;
            p[0 * (size_t)N] = acc[tm][tn][0];
            p[1 * (size_t)N] = acc[tm][tn][1];
            p[2 * (size_t)N] = acc[tm][tn][2];
            p[3 * (size_t)N] = acc[tm][tn][3];
        }
    }
}

// ---------------------------------------------------------------------------
extern "C" void kernel_launch(void* const* d_in, const int* in_sizes, int n_in,
                              void* d_out, int out_size, void* d_ws, size_t ws_size,
                              hipStream_t stream) {
    const float* x      = (const float*)d_in[0];
    const int*   wint   = (const int*)d_in[1];
    const float* wscale = (const float*)d_in[2];
    const float* lA     = (const float*)d_in[3];
    const float* lB     = (const float*)d_in[4];
    float* out = (float*)d_out;

    __bf16* Xb = (__bf16*)d_ws;                                   // M*K*2 = 64 MiB
    __bf16* Wb = (__bf16*)((char*)d_ws + (size_t)M * K * 2);      // N*K*2 = 32 MiB

    qlora_cast_x<<<16384, 256, 0, stream>>>(x, Xb);
    qlora_prep_w<<<4096, 256, 0, stream>>>(wint, wscale, lA, lB, Wb);
    qlora_gemm_bt<<<dim3(N / 128, M / 128), 256, 0, stream>>>(Xb, Wb, out);
}

// Round 3
// 617.706 us; speedup vs baseline: 1.1377x; 1.1130x over previous
//
#include <hip/hip_runtime.h>

// Shapes (fixed by the reference): B=4, S=2048 -> M=8192; D_IN=K=4096; D_OUT=N=4096; R=16
constexpr int M = 8192;
constexpr int N = 4096;
constexpr int K = 4096;
constexpr float SCALING = 2.0f; // 32/16

typedef __bf16 bf16x8 __attribute__((ext_vector_type(8)));
typedef __bf16 bf16x4 __attribute__((ext_vector_type(4)));
typedef float  f32x4  __attribute__((ext_vector_type(4)));

// ---------------------------------------------------------------------------
// Kernel 1: cast x (fp32) -> bf16, 8 elements / thread
// ---------------------------------------------------------------------------
__global__ __launch_bounds__(256) void qlora_cast_x(const float* __restrict__ x,
                                                    __bf16* __restrict__ xb) {
    const size_t i = ((size_t)blockIdx.x * 256 + threadIdx.x) * 8;
    const float4 v0 = *(const float4*)(x + i);
    const float4 v1 = *(const float4*)(x + i + 4);
    bf16x8 o;
    o[0] = (__bf16)v0.x; o[1] = (__bf16)v0.y; o[2] = (__bf16)v0.z; o[3] = (__bf16)v0.w;
    o[4] = (__bf16)v1.x; o[5] = (__bf16)v1.y; o[6] = (__bf16)v1.z; o[7] = (__bf16)v1.w;
    *(bf16x8*)(xb + i) = o;
}

// ---------------------------------------------------------------------------
// Kernel 2: W_eff[o,i] = w_int[o,i]*scale + 2 * sum_r loraB[o,r]*loraA[r,i]  (bf16)
// ---------------------------------------------------------------------------
__global__ __launch_bounds__(256) void qlora_prep_w(const int* __restrict__ wi,
                                                    const float* __restrict__ wscale,
                                                    const float* __restrict__ lA,
                                                    const float* __restrict__ lB,
                                                    __bf16* __restrict__ W) {
    const int o = blockIdx.x;
    const float s = wscale[0];
    float b[16];
#pragma unroll
    for (int r = 0; r < 16; ++r) b[r] = lB[o * 16 + r];

#pragma unroll
    for (int it = 0; it < 4; ++it) {
        const int i0 = it * 1024 + threadIdx.x * 4;
        const int4 w4 = *(const int4*)(wi + (size_t)o * K + i0);
        float a0 = 0.f, a1 = 0.f, a2 = 0.f, a3 = 0.f;
#pragma unroll
        for (int r = 0; r < 16; ++r) {
            const float4 a4 = *(const float4*)(lA + r * K + i0);
            a0 += b[r] * a4.x; a1 += b[r] * a4.y;
            a2 += b[r] * a4.z; a3 += b[r] * a4.w;
        }
        bf16x4 v;
        v[0] = (__bf16)((float)w4.x * s + SCALING * a0);
        v[1] = (__bf16)((float)w4.y * s + SCALING * a1);
        v[2] = (__bf16)((float)w4.z * s + SCALING * a2);
        v[3] = (__bf16)((float)w4.w * s + SCALING * a3);
        *(bf16x4*)(W + (size_t)o * K + i0) = v;
    }
}

// ---------------------------------------------------------------------------
// Kernel 3: C[M,N] = Xbf[M,K] @ Wbf[N,K]^T
// m97 structure, BK=64 (half the barrier-drain events of BK=32).
//
// LDS tile: 128 rows x 64 k, row stride 128 B. 16B chunk c (c=0..7) of row r
// is stored at slot c ^ (r & 7)  -> read-side bank spread: slot varies with
// lb&7 -> 8 bank-groups x 2 lanes = 2-way = free (m136).
// Staging: one async16 covers 8 rows x 8 slots; lane l -> row l>>3, slot l&7,
// fetching global chunk (l&7) ^ (l>>3)  [slot XOR row].
// LDS addr = rowtile*1024B + lane*16B  == wave-uniform base + lane*16. OK.
// ---------------------------------------------------------------------------
__device__ __forceinline__ void async16(const __bf16* g, __bf16* l) {
    __builtin_amdgcn_global_load_lds(
        (const __attribute__((address_space(1))) unsigned int*)(unsigned long long)g,
        (__attribute__((address_space(3))) unsigned int*)(unsigned int)(unsigned long long)l,
        16, 0, 0);
}

__global__ __launch_bounds__(256) void qlora_gemm_bt(const __bf16* __restrict__ A,
                                                     const __bf16* __restrict__ B,
                                                     float* __restrict__ C) {
    __shared__ __align__(16) __bf16 As[128 * 64];
    __shared__ __align__(16) __bf16 Bs[128 * 64];

    const int tid  = threadIdx.x;
    const int w    = tid >> 6;      // wave 0..3
    const int lane = tid & 63;
    const int quad = lane >> 4;     // 0..3
    const int lb   = lane & 15;
    const int wm   = w >> 1;        // 0..1
    const int wn   = w & 1;         // 0..1

    // staging: lane -> row (within 8-row tile), slot, swizzled global chunk
    const int r8   = lane >> 3;                 // 0..7
    const int slot = lane & 7;                  // 0..7
    const int q_sw = (slot ^ r8) * 8;           // global k-offset (elements)

    const size_t mBase = (size_t)blockIdx.y * 128;
    const size_t nBase = (size_t)blockIdx.x * 128;

    // wave w stages A row-tiles {4w..4w+3} and B row-tiles {4w..4w+3} (8 rows each)
    const __bf16* gA[4];
    const __bf16* gB[4];
    __bf16* lA[4];
    __bf16* lB[4];
#pragma unroll
    for (int j = 0; j < 4; ++j) {
        const int rt = w * 4 + j;               // row-tile 0..15
        gA[j] = A + (mBase + rt * 8 + r8) * K + q_sw;
        gB[j] = B + (nBase + rt * 8 + r8) * K + q_sw;
        lA[j] = As + rt * 512;                  // 8 rows * 64 elems
        lB[j] = Bs + rt * 512;
    }

    f32x4 acc[4][4] = {};

    for (int kt = 0; kt < K; kt += 64) {
#pragma unroll
        for (int j = 0; j < 4; ++j) async16(gA[j] + kt, lA[j]);
#pragma unroll
        for (int j = 0; j < 4; ++j) async16(gB[j] + kt, lB[j]);
        __syncthreads();   // vmcnt(0) drain + barrier: tiles visible

#pragma unroll
        for (int s = 0; s < 2; ++s) {           // two 32-k sub-steps
            bf16x8 af[4], bfr[4];
#pragma unroll
            for (int t = 0; t < 4; ++t) {
                const int rowA = wm * 64 + t * 16 + lb;
                const int rowB = wn * 64 + t * 16 + lb;
                const int sl   = ((s * 4 + quad) ^ (lb & 7)) * 8;
                af[t]  = *(const bf16x8*)(As + rowA * 64 + sl);
                bfr[t] = *(const bf16x8*)(Bs + rowB * 64 + sl);
            }
#pragma unroll
            for (int tm = 0; tm < 4; ++tm)
#pragma unroll
                for (int tn = 0; tn < 4; ++tn)
                    acc[tm][tn] = __builtin_amdgcn_mfma_f32_16x16x32_bf16(
                        af[tm], bfr[tn], acc[tm][tn], 0, 0, 0);
        }
        __syncthreads();   // all waves done reading before next overwrite
    }

    // Epilogue: D layout col = lane&15, row = quad*4 + reg
#pragma unroll
    for (int tm = 0; tm < 4; ++tm) {
        const size_t m0 = mBase + wm * 64 + tm * 16 + quad * 4;
#pragma unroll
        for (int tn = 0; tn < 4; ++tn) {
            const size_t n0 = nBase + wn * 64 + tn * 16 + lb;
            float* p = C + m0 * N + n0;
            p[0 * (size_t)N] = acc[tm][tn][0];
            p[1 * (size_t)N] = acc[tm][tn][1];
            p[2 * (size_t)N] = acc[tm][tn][2];
            p[3 * (size_t)N] = acc[tm][tn][3];
        }
    }
}

// ---------------------------------------------------------------------------
extern "C" void kernel_launch(void* const* d_in, const int* in_sizes, int n_in,
                              void* d_out, int out_size, void* d_ws, size_t ws_size,
                              hipStream_t stream) {
    const float* x      = (const float*)d_in[0];
    const int*   wint   = (const int*)d_in[1];
    const float* wscale = (const float*)d_in[2];
    const float* lA     = (const float*)d_in[3];
    const float* lB     = (const float*)d_in[4];
    float* out = (float*)d_out;

    __bf16* Xb = (__bf16*)d_ws;                                   // M*K*2 = 64 MiB
    __bf16* Wb = (__bf16*)((char*)d_ws + (size_t)M * K * 2);      // N*K*2 = 32 MiB

    qlora_cast_x<<<16384, 256, 0, stream>>>(x, Xb);
    qlora_prep_w<<<4096, 256, 0, stream>>>(wint, wscale, lA, lB, Wb);
    qlora_gemm_bt<<<dim3(N / 128, M / 128), 256, 0, stream>>>(Xb, Wb, out);
}